// Round 15
// baseline (1227.262 us; speedup 1.0000x reference)
//
#include <hip/hip_runtime.h>
#include <hip/hip_fp16.h>

#define LQ 384
#define DF 64
#define NWIN 16
#define PERW 15      // NG + NF
#define STEPW 16     // 1 + NG + NF
#define NPAIR 240    // NWIN * PERW
#define NWAVE 6      // row-slabs (producer waves and consumer waves each)
#define PW 64        // panel width (cols per round)
#define NPANEL 6     // 384 / PW
#define NROUND2 12   // NPANEL + NWAVE - 1 + 1 (producer lead)
#define BSTH 68      // fp16 B LDS row stride (halfs); 136 B, 8B-aligned
#define DRS 68       // fp16 D-tile row stride (halfs); 136 B, 8B-aligned
#define C2  0.28853900817779268f   // 1/(5*ln2)  (pre-scale: R' = R*C2)
#define L2C 3.4657359027997265f    // 5*ln2      (unscale at extraction)
#define BIGS (1e9f * C2)           // BIG in scaled domain

typedef float v2f __attribute__((ext_vector_type(2)));

__device__ __forceinline__ float fexp2(float x) { return __builtin_amdgcn_exp2f(x); }
__device__ __forceinline__ float flog2(float x) { return __builtin_amdgcn_logf(x); }

// wave_shr:1 -- lane l gets lane l-1's value (VALU pipe). lane0 keeps own (fixed up).
__device__ __forceinline__ float wshr1f(float x) {
  int xi = __float_as_int(x);
  return __int_as_float(__builtin_amdgcn_update_dpp(xi, xi, 0x138, 0xF, 0xF, false));
}
__device__ __forceinline__ float rdlane(float v, int l) {
  return __int_as_float(__builtin_amdgcn_readlane(__float_as_int(v), l));
}
__device__ __forceinline__ v2f cvt2(uint u) {
  v2f r;
  r.x = __half2float(__ushort_as_half((ushort)(u & 0xffffu)));
  r.y = __half2float(__ushort_as_half((ushort)(u >> 16)));
  return r;
}

// ---------------------------------------------------------------------------
// Producer-consumer soft-DTW, PW=64 (r12/r14 layout; validated numerics).
// KEY FIX: amdgpu_waves_per_eu(3,3) pins the register budget to the LDS-
// implied occupancy (1 block/CU = 3 waves/EU -> 168 VGPRs). Without it the
// compiler budgeted for 6 waves/EU (84 VGPRs) and spilled the 64-float D-row
// array to scratch (722 MB WRITE_SIZE in r12/r14).
// ---------------------------------------------------------------------------
__global__ __launch_bounds__(768) __attribute__((amdgpu_waves_per_eu(3, 3)))
void sdtw_kernel(const float* __restrict__ data,
                 const int* __restrict__ lens,
                 float* __restrict__ dist) {
  __shared__ __align__(16) __half BshH[LQ * BSTH];           // 52224 B (B in fp16)
  __shared__ __align__(16) __half DtH[2][NWAVE][64 * DRS];   // 104448 B (D*C2, fp16)
  __shared__ __align__(16) float  sqA[LQ];                   // 1536 B
  __shared__ __align__(16) float  sqB[LQ];                   // 1536 B
  __shared__ __align__(16) float  bnd[NWAVE][2][68];         // 3264 B  (163008 total)

  const int p_id = blockIdx.x;
  const int wwin = p_id / PERW;
  const int o = p_id - wwin * PERW;
  const int aRow = wwin * STEPW;
  const int bRow = aRow + 1 + o;
  const int la = lens[aRow];
  const int lb = lens[bRow];
  const int tid = threadIdx.x;
  const int w = tid >> 6;        // 0..11
  const int lane = tid & 63;

  const float* __restrict__ A  = data + (size_t)aRow * LQ * DF;
  const float* __restrict__ Bp = data + (size_t)bRow * LQ * DF;

  // ---- stage B (fp16) into LDS; sqA/sqB from fp32 global ----
  {
    const float4* B4 = (const float4*)Bp;
    for (int q = tid; q < LQ * 16; q += 768) {
      float4 v = B4[q];
      int row = q >> 4, c4 = (q & 15) << 2;
      uint u0 = __half_as_ushort(__float2half(v.x)) |
                ((uint)__half_as_ushort(__float2half(v.y)) << 16);
      uint u1 = __half_as_ushort(__float2half(v.z)) |
                ((uint)__half_as_ushort(__float2half(v.w)) << 16);
      uint2 qq; qq.x = u0; qq.y = u1;
      *(uint2*)&BshH[row * BSTH + c4] = qq;     // 8B-aligned
    }
  }
  {
    const float* src = (tid < LQ) ? (A + (size_t)tid * DF) : (Bp + (size_t)(tid - LQ) * DF);
    const float4* S4 = (const float4*)src;
    float s = 0.f;
#pragma unroll
    for (int k = 0; k < 16; ++k) {
      float4 v = S4[k];
      s = fmaf(v.x, v.x, s); s = fmaf(v.y, v.y, s);
      s = fmaf(v.z, v.z, s); s = fmaf(v.w, v.w, s);
    }
    if (tid < LQ) sqA[tid] = s; else sqB[tid - LQ] = s;
  }
  __syncthreads();

  // extraction target: R[la][lb] at DP wave wt, lane it, panel pt
  const int wt = (la - 1) >> 6;
  const int it = (la - 1) & 63;
  const int pt = (lb - 1) >> 6;                 // PW=64 panels
  const int tstar = it + ((lb - 1) & 63);
  const int rstar2 = wt + pt + 1;               // consumer round index
  const float scale = L2C / (float)(la + lb);

  if (w < NWAVE) {
    // =====================  GEMM (producer) waves  =========================
    const int g = w;
    const int rg = lane >> 3, cg = lane & 7;    // 8 rows x 4 cols per lane
    const bool gActive = (64 * g < la);
    const float4* A4g = (const float4*)(A + (size_t)(64 * g + 8 * rg) * DF);
    float sa8[8];
    *(float4*)&sa8[0] = *(const float4*)&sqA[64 * g + 8 * rg];
    *(float4*)&sa8[4] = *(const float4*)&sqA[64 * g + 8 * rg + 4];

    for (int rr = 0; rr < NROUND2; ++rr) {
      __syncthreads();
      const int p = rr - g;
      if ((unsigned)p < (unsigned)NPANEL && gActive && (64 * p < lb)) {
        __half* DtW = &DtH[rr & 1][g][0];
#pragma unroll
        for (int pass = 0; pass < 2; ++pass) {
          v2f acc[8][4];
#pragma unroll
          for (int a_ = 0; a_ < 8; ++a_)
#pragma unroll
            for (int b_ = 0; b_ < 4; ++b_) { acc[a_][b_].x = 0.f; acc[a_][b_].y = 0.f; }
          const __half* Bb = &BshH[(PW * p + 32 * pass + 4 * cg) * BSTH];
#pragma unroll
          for (int kk = 0; kk < 16; ++kk) {
            v2f b01[4], b23[4];
#pragma unroll
            for (int cc = 0; cc < 4; ++cc) {
              uint2 raw = *(const uint2*)&Bb[cc * BSTH + 4 * kk];
              b01[cc] = cvt2(raw.x);
              b23[cc] = cvt2(raw.y);
            }
#pragma unroll
            for (int rrr = 0; rrr < 8; ++rrr) {
              float4 v = A4g[rrr * 16 + kk];
              v2f a01, a23;
              a01.x = v.x; a01.y = v.y; a23.x = v.z; a23.y = v.w;
#pragma unroll
              for (int cc = 0; cc < 4; ++cc) {
                acc[rrr][cc] = __builtin_elementwise_fma(a01, b01[cc], acc[rrr][cc]);
                acc[rrr][cc] = __builtin_elementwise_fma(a23, b23[cc], acc[rrr][cc]);
              }
            }
          }
          // epilogue: D' = (sqA+sqB-2*dot)*C2 -> fp16 RTN, row-major b64 store
          float4 sb = *(const float4*)&sqB[PW * p + 32 * pass + 4 * cg];
          float sbv[4] = {sb.x, sb.y, sb.z, sb.w};
#pragma unroll
          for (int rrr = 0; rrr < 8; ++rrr) {
            float v0 = (sa8[rrr] + sbv[0] - 2.f * (acc[rrr][0].x + acc[rrr][0].y)) * C2;
            float v1 = (sa8[rrr] + sbv[1] - 2.f * (acc[rrr][1].x + acc[rrr][1].y)) * C2;
            float v2 = (sa8[rrr] + sbv[2] - 2.f * (acc[rrr][2].x + acc[rrr][2].y)) * C2;
            float v3 = (sa8[rrr] + sbv[3] - 2.f * (acc[rrr][3].x + acc[rrr][3].y)) * C2;
            uint2 q;
            q.x = __half_as_ushort(__float2half(v0)) |
                  ((uint)__half_as_ushort(__float2half(v1)) << 16);
            q.y = __half_as_ushort(__float2half(v2)) |
                  ((uint)__half_as_ushort(__float2half(v3)) << 16);
            *(uint2*)&DtW[(8 * rg + rrr) * DRS + 4 * cg + 32 * pass] = q;
          }
        }
      }
    }
  } else {
    // =====================  DP (consumer) waves  ===========================
    const int d = w - NWAVE;                    // 0..5, owns rows 64d+1..64d+64
    const bool dActive = (64 * d < la);
    const int dn = (d + 1 < NWAVE) ? (d + 1) : 0;
    float leftR = BIGS;

    for (int rr = 0; rr < NROUND2; ++rr) {
      __syncthreads();
      const int p = rr - 1 - d;
      if ((unsigned)p < (unsigned)NPANEL && dActive && (64 * p < lb)) {
        const __half* DtW = &DtH[(rr - 1) & 1][d][0];

        float* bndR = &bnd[d][rr & 1][0];
        float* bndW = &bnd[dn][(rr + 1) & 1][0];
        const bool wr63 = (lane == 63) && (d + 1 < NWAVE) && (64 * (d + 1) < la);
        if (wr63) bndW[0] = leftR;

        // ---- preload D row rotated, as TWO float[32] (literal indices) -----
        const ushort* rowb = (const ushort*)&DtW[lane * DRS];
        float hvA[32], hvB[32];
#pragma unroll
        for (int pp = 0; pp < 32; ++pp) {
          int src = (pp - lane) & 31;
          hvA[pp] = __half2float(__ushort_as_half(rowb[src]));
          hvB[pp] = __half2float(__ushort_as_half(rowb[32 + src]));
        }

        // ---- boundary row (65 floats) into regs ----------------------------
        float vbnd = BIGS, b64v = BIGS;
        if (d > 0) { vbnd = bndR[lane]; b64v = bndR[64]; }

        float cur = leftR;
        float extv = 0.f;
        float s2;
        {
          float fix0 = (d == 0) ? ((p == 0) ? 0.f : BIGS) : rdlane(vbnd, 0);
          s2 = (lane == 0) ? fix0 : cur;
        }
        const bool extRound = (d == wt) && (rr == rstar2);

#define STEP(T) do {                                                        \
        float s1 = wshr1f(cur);                                             \
        if ((T) < 64) {                                                     \
          float bup = ((T) < 63) ? rdlane(vbnd, (T) + 1) : b64v;            \
          bup = (d == 0) ? BIGS : bup;                                      \
          s1 = (lane == 0) ? bup : s1;                                      \
        }                                                                   \
        int jl = (T) - lane;                                                \
        float dv = ((unsigned)jl < 32u) ? hvA[(T) & 31] : hvB[(T) & 31];    \
        float m = fminf(s2, fminf(s1, cur));                                \
        float e = fexp2(m - s2) + fexp2(m - s1) + fexp2(m - cur);           \
        float val = dv + m - flog2(e);                                      \
        s2 = s1;                                                            \
        if (extRound && tstar == (T) && lane == it) extv = val;             \
        if ((unsigned)jl < 64u) {                                           \
          cur = val;                                                        \
          if ((T) >= 63) { if (wr63) bndW[jl + 1] = val; }                  \
        }                                                                   \
      } while (0)

#define S8(T) STEP((T)); STEP((T)+1); STEP((T)+2); STEP((T)+3); \
              STEP((T)+4); STEP((T)+5); STEP((T)+6); STEP((T)+7);

        S8(0)   S8(8)   S8(16)  S8(24)
        S8(32)  S8(40)  S8(48)  S8(56)
        S8(64)  S8(72)  S8(80)  S8(88)
        S8(96)  S8(104) S8(112) S8(120)
#undef S8
#undef STEP
        if (extRound && lane == it) dist[p_id] = extv * scale;
        leftR = cur;
      }
    }
  }
}

// ---------------------------------------------------------------------------
// Loss reduction over 16 windows (validated rounds 1-14).
// ---------------------------------------------------------------------------
__device__ __forceinline__ float median5(const float* v) {
#pragma unroll
  for (int i = 0; i < 5; ++i) {
    int c = 0;
#pragma unroll
    for (int j = 0; j < 5; ++j)
      c += (v[j] < v[i]) || ((v[j] == v[i]) && (j < i));
    if (c == 2) return v[i];
  }
  return v[0];
}

__global__ void loss_kernel(const float* __restrict__ dist, float* __restrict__ out) {
  __shared__ float acc[NWIN];
  const int w = threadIdx.x;
  if (w < NWIN) {
    float dg[5], dn[10];
#pragma unroll
    for (int g = 0; g < 5; ++g)  dg[g] = dist[w * PERW + g];
#pragma unroll
    for (int n = 0; n < 10; ++n) dn[n] = dist[w * PERW + 5 + n];

    float lk = 0.f; int nz = 0;
#pragma unroll
    for (int g = 0; g < 5; ++g)
#pragma unroll
      for (int n = 0; n < 10; ++n) {
        float t = dg[g] + 1.0f - dn[n];
        if (t > 0.f) { lk += t; ++nz; }
      }
    float lv = lk / (1.0f + (float)nz);

    float sp = 0.f;
#pragma unroll
    for (int g = 0; g < 5; ++g) sp += dg[g];
    float only_pos = sp * (0.01f / 5.0f);

    float mg = median5(dg);
    float ms = median5(dn);

    int err = 0;
#pragma unroll
    for (int g = 0; g < 5; ++g) {
      err += ((dg[g] < mg) && (dn[g] < mg));
      err += ((dg[g] > ms) && (dn[g] > ms));
      err += ((dg[g] < mg) && (dn[5 + g] < mg));
      err += ((dg[g] > ms) && (dn[5 + g] > ms));
    }
    float offset = (float)err * (1.0f / 50.0f);

    acc[w] = lv + only_pos + offset;
  }
  __syncthreads();
  if (w == 0) {
    float s = 0.f;
#pragma unroll
    for (int i = 0; i < NWIN; ++i) s += acc[i];
    out[0] = s / (float)NWIN;
  }
}

// ---------------------------------------------------------------------------
extern "C" void kernel_launch(void* const* d_in, const int* in_sizes, int n_in,
                              void* d_out, int out_size, void* d_ws, size_t ws_size,
                              hipStream_t stream) {
  const float* data = (const float*)d_in[0];
  const int* lens   = (const int*)d_in[1];
  float* dist = (float*)d_ws;

  sdtw_kernel<<<NPAIR, 768, 0, stream>>>(data, lens, dist);
  loss_kernel<<<1, 64, 0, stream>>>(dist, (float*)d_out);
}

// Round 16
// 163.930 us; speedup vs baseline: 7.4865x; 7.4865x over previous
//
#include <hip/hip_runtime.h>
#include <hip/hip_fp16.h>

#define LQ 384
#define DF 64
#define NWIN 16
#define PERW 15      // NG + NF
#define STEPW 16     // 1 + NG + NF
#define NPAIR 240    // NWIN * PERW
#define NWAVE 6      // row-slabs (producer waves and consumer waves each)
#define PW 32        // panel width (cols per round)
#define NPANEL 12    // 384 / PW
#define NROUND2 18   // NPANEL + NWAVE - 1 + 1 (producer lead)
#define BST 66       // B LDS row stride (floats)
#define DRS 36       // fp16 D-tile ROW stride (halfs); 72 B, 8B-aligned
#define C2  0.28853900817779268f   // 1/(5*ln2)  (pre-scale: R' = R*C2)
#define L2C 3.4657359027997265f    // 5*ln2      (unscale at extraction)
#define BIGS (1e9f * C2)           // BIG in scaled domain

typedef float v2f __attribute__((ext_vector_type(2)));

__device__ __forceinline__ float fexp2(float x) { return __builtin_amdgcn_exp2f(x); }
__device__ __forceinline__ float flog2(float x) { return __builtin_amdgcn_logf(x); }

// wave_shr:1 -- lane l gets lane l-1's value (VALU pipe). lane0 keeps own (fixed up).
__device__ __forceinline__ float wshr1f(float x) {
  int xi = __float_as_int(x);
  return __int_as_float(__builtin_amdgcn_update_dpp(xi, xi, 0x138, 0xF, 0xF, false));
}
__device__ __forceinline__ float rdlane(float v, int l) {
  return __int_as_float(__builtin_amdgcn_readlane(__float_as_int(v), l));
}

// ---------------------------------------------------------------------------
// Producer-consumer soft-DTW (r13 structure, validated 167us / absmax 0.0).
// This round: softmin uses the min3/med3/max3 identity -- one of the three
// exp2 args is exactly 0, so e = 1 + exp2(m-med) + exp2(m-max). Cuts the
// trans-pipe ops per step 4 -> 3 (trans is quarter-rate = the dominant
// per-step issue cost) with bit-identical subtractions.
// ---------------------------------------------------------------------------
__global__ __launch_bounds__(768, 3) void sdtw_kernel(const float* __restrict__ data,
                                                      const int* __restrict__ lens,
                                                      float* __restrict__ dist) {
  __shared__ __align__(16) float  Bsh[LQ * BST];             // 101376 B
  __shared__ __align__(16) __half DtH[2][NWAVE][64 * DRS];   // 55296 B (D*C2, row-major)
  __shared__ __align__(16) float  sqA[LQ];                   // 1536 B
  __shared__ __align__(16) float  sqB[LQ];                   // 1536 B
  __shared__ __align__(16) float  bnd[NWAVE][2][36];         // 1728 B  (161472 total)

  const int p_id = blockIdx.x;
  const int wwin = p_id / PERW;
  const int o = p_id - wwin * PERW;
  const int aRow = wwin * STEPW;
  const int bRow = aRow + 1 + o;
  const int la = lens[aRow];
  const int lb = lens[bRow];
  const int tid = threadIdx.x;
  const int w = tid >> 6;        // 0..11
  const int lane = tid & 63;

  const float* __restrict__ A  = data + (size_t)aRow * LQ * DF;
  const float* __restrict__ Bp = data + (size_t)bRow * LQ * DF;

  // ---- stage B into LDS (768 threads); sqA (threads 0..383 from global) ----
  {
    const float4* B4 = (const float4*)Bp;
    for (int q = tid; q < LQ * 16; q += 768) {
      float4 v = B4[q];
      int row = q >> 4, c4 = (q & 15) << 2;
      float* dst = &Bsh[row * BST + c4];
      ((float2*)dst)[0] = make_float2(v.x, v.y);
      ((float2*)dst)[1] = make_float2(v.z, v.w);
    }
  }
  if (tid < LQ) {
    const float4* A4 = (const float4*)(A + (size_t)tid * DF);
    float s = 0.f;
#pragma unroll
    for (int k = 0; k < 16; ++k) {
      float4 v = A4[k];
      s = fmaf(v.x, v.x, s); s = fmaf(v.y, v.y, s);
      s = fmaf(v.z, v.z, s); s = fmaf(v.w, v.w, s);
    }
    sqA[tid] = s;
  }
  __syncthreads();
  if (tid < LQ) {
    float s = 0.f;
    const float2* row = (const float2*)&Bsh[tid * BST];
#pragma unroll
    for (int k = 0; k < 32; ++k) { float2 v = row[k]; s = fmaf(v.x, v.x, s); s = fmaf(v.y, v.y, s); }
    sqB[tid] = s;
  }
  __syncthreads();

  // extraction target: R[la][lb] at DP wave wt, lane it, panel pt
  const int wt = (la - 1) >> 6;
  const int it = (la - 1) & 63;
  const int pt = (lb - 1) >> 5;
  const int tstar = it + ((lb - 1) & 31);
  const int rstar2 = wt + pt + 1;               // consumer round index
  const float scale = L2C / (float)(la + lb);

  if (w < NWAVE) {
    // =====================  GEMM (producer) waves  =========================
    const int g = w;
    const int rg = lane >> 3, cg = lane & 7;    // 8 rows x 4 cols per lane
    const bool gActive = (64 * g < la);
    const float4* A4g = (const float4*)(A + (size_t)(64 * g + 8 * rg) * DF);
    float sa8[8];
    *(float4*)&sa8[0] = *(const float4*)&sqA[64 * g + 8 * rg];
    *(float4*)&sa8[4] = *(const float4*)&sqA[64 * g + 8 * rg + 4];

    for (int rr = 0; rr < NROUND2; ++rr) {
      __syncthreads();
      const int p = rr - g;
      if ((unsigned)p < (unsigned)NPANEL && gActive && (32 * p < lb)) {
        __half* DtW = &DtH[rr & 1][g][0];
        // ----- GEMM: B from LDS (float2), A from global/L1 (r3-validated) ---
        v2f acc[8][4];
#pragma unroll
        for (int a_ = 0; a_ < 8; ++a_)
#pragma unroll
          for (int b_ = 0; b_ < 4; ++b_) { acc[a_][b_].x = 0.f; acc[a_][b_].y = 0.f; }
        const float* Bb = &Bsh[(PW * p + 4 * cg) * BST];
#pragma unroll
        for (int kk = 0; kk < 16; ++kk) {
          v2f b0[4], b1[4];
#pragma unroll
          for (int cc = 0; cc < 4; ++cc) {
            b0[cc] = *(const v2f*)&Bb[cc * BST + 4 * kk];
            b1[cc] = *(const v2f*)&Bb[cc * BST + 4 * kk + 2];
          }
#pragma unroll
          for (int rrr = 0; rrr < 8; ++rrr) {
            float4 v = A4g[rrr * 16 + kk];
            v2f a0, a1;
            a0.x = v.x; a0.y = v.y; a1.x = v.z; a1.y = v.w;
#pragma unroll
            for (int cc = 0; cc < 4; ++cc) {
              acc[rrr][cc] = __builtin_elementwise_fma(a0, b0[cc], acc[rrr][cc]);
              acc[rrr][cc] = __builtin_elementwise_fma(a1, b1[cc], acc[rrr][cc]);
            }
          }
        }
        // ----- epilogue: D' = (sqA+sqB-2*dot)*C2 -> fp16 RTN, row-major b64 --
        float4 sb = *(const float4*)&sqB[PW * p + 4 * cg];
        float sbv[4] = {sb.x, sb.y, sb.z, sb.w};
        float vr[8][4];
#pragma unroll
        for (int cc = 0; cc < 4; ++cc) {
#pragma unroll
          for (int rrr = 0; rrr < 8; ++rrr)
            vr[rrr][cc] = (sa8[rrr] + sbv[cc] - 2.f * (acc[rrr][cc].x + acc[rrr][cc].y)) * C2;
        }
#pragma unroll
        for (int rrr = 0; rrr < 8; ++rrr) {
          uint h0 = __half_as_ushort(__float2half(vr[rrr][0]));
          uint h1 = __half_as_ushort(__float2half(vr[rrr][1]));
          uint h2 = __half_as_ushort(__float2half(vr[rrr][2]));
          uint h3 = __half_as_ushort(__float2half(vr[rrr][3]));
          uint2 q;
          q.x = h0 | (h1 << 16);
          q.y = h2 | (h3 << 16);
          *(uint2*)&DtW[(8 * rg + rrr) * DRS + 4 * cg] = q;   // 8B-aligned
        }
      }
    }
  } else {
    // =====================  DP (consumer) waves  ===========================
    const int d = w - NWAVE;                    // 0..5, owns rows 64d+1..64d+64
    const bool dActive = (64 * d < la);
    const int dn = (d + 1 < NWAVE) ? (d + 1) : 0;
    const int l5 = lane & 31;
    float leftR = BIGS;

    for (int rr = 0; rr < NROUND2; ++rr) {
      __syncthreads();
      const int p = rr - 1 - d;
      if ((unsigned)p < (unsigned)NPANEL && dActive && (32 * p < lb)) {
        const __half* DtW = &DtH[(rr - 1) & 1][d][0];

        float* bndR = &bnd[d][rr & 1][0];
        float* bndW = &bnd[dn][(rr + 1) & 1][0];
        const bool wr63 = (lane == 63) && (d + 1 < NWAVE) && (64 * (d + 1) < la);
        if (wr63) bndW[0] = leftR;

        // ---- preload D row, rotated, as FLOAT (promotes to 32 VGPRs) ------
        const __half* baseA = DtW + (lane * DRS - l5);
        const __half* baseB = baseA + 32;
        float hv[32];
#pragma unroll
        for (int pp = 0; pp < 32; ++pp)
          hv[pp] = __half2float((pp < l5) ? baseB[pp] : baseA[pp]);

        // ---- preload boundary row into one VGPR per lane -------------------
        float vbnd = BIGS;
        if (d > 0 && lane < 36) vbnd = bndR[lane];

        float cur = leftR;
        float extv = 0.f;
        float s2;
        {
          float fix0 = (d == 0) ? ((p == 0) ? 0.f : BIGS) : rdlane(vbnd, 0);
          s2 = (lane == 0) ? fix0 : cur;
        }
        const bool extRound = (d == wt) && (rr == rstar2);

#define STEP(T) do {                                                        \
        float s1 = wshr1f(cur);                                             \
        if ((T) < 32) {                                                     \
          float bup = rdlane(vbnd, (T) + 1);                                \
          s1 = (lane == 0) ? bup : s1;                                      \
        }                                                                   \
        float dv = hv[(T) & 31];                                            \
        float m  = fminf(s2, fminf(s1, cur));            /* v_min3 */       \
        float md = __builtin_amdgcn_fmed3f(s2, s1, cur); /* v_med3 */       \
        float mx = fmaxf(s2, fmaxf(s1, cur));            /* v_max3 */       \
        float e = 1.0f + fexp2(m - md) + fexp2(m - mx);                     \
        float val = dv + m - flog2(e);                                      \
        s2 = s1;                                                            \
        if (extRound && tstar == (T) && lane == it) extv = val;             \
        int jl = (T) - lane;                                                \
        if ((unsigned)jl < 32u) {                                           \
          cur = val;                                                        \
          if ((T) >= 63) { if (wr63) bndW[jl + 1] = val; }                  \
        }                                                                   \
      } while (0)

#pragma unroll
        for (int T = 0; T < 96; ++T) STEP(T);
#undef STEP
        if (extRound && lane == it) dist[p_id] = extv * scale;
        leftR = cur;
      }
    }
  }
}

// ---------------------------------------------------------------------------
// Loss reduction over 16 windows (validated rounds 1-15).
// ---------------------------------------------------------------------------
__device__ __forceinline__ float median5(const float* v) {
#pragma unroll
  for (int i = 0; i < 5; ++i) {
    int c = 0;
#pragma unroll
    for (int j = 0; j < 5; ++j)
      c += (v[j] < v[i]) || ((v[j] == v[i]) && (j < i));
    if (c == 2) return v[i];
  }
  return v[0];
}

__global__ void loss_kernel(const float* __restrict__ dist, float* __restrict__ out) {
  __shared__ float acc[NWIN];
  const int w = threadIdx.x;
  if (w < NWIN) {
    float dg[5], dn[10];
#pragma unroll
    for (int g = 0; g < 5; ++g)  dg[g] = dist[w * PERW + g];
#pragma unroll
    for (int n = 0; n < 10; ++n) dn[n] = dist[w * PERW + 5 + n];

    float lk = 0.f; int nz = 0;
#pragma unroll
    for (int g = 0; g < 5; ++g)
#pragma unroll
      for (int n = 0; n < 10; ++n) {
        float t = dg[g] + 1.0f - dn[n];
        if (t > 0.f) { lk += t; ++nz; }
      }
    float lv = lk / (1.0f + (float)nz);

    float sp = 0.f;
#pragma unroll
    for (int g = 0; g < 5; ++g) sp += dg[g];
    float only_pos = sp * (0.01f / 5.0f);

    float mg = median5(dg);
    float ms = median5(dn);

    int err = 0;
#pragma unroll
    for (int g = 0; g < 5; ++g) {
      err += ((dg[g] < mg) && (dn[g] < mg));
      err += ((dg[g] > ms) && (dn[g] > ms));
      err += ((dg[g] < mg) && (dn[5 + g] < mg));
      err += ((dg[g] > ms) && (dn[5 + g] > ms));
    }
    float offset = (float)err * (1.0f / 50.0f);

    acc[w] = lv + only_pos + offset;
  }
  __syncthreads();
  if (w == 0) {
    float s = 0.f;
#pragma unroll
    for (int i = 0; i < NWIN; ++i) s += acc[i];
    out[0] = s / (float)NWIN;
  }
}

// ---------------------------------------------------------------------------
extern "C" void kernel_launch(void* const* d_in, const int* in_sizes, int n_in,
                              void* d_out, int out_size, void* d_ws, size_t ws_size,
                              hipStream_t stream) {
  const float* data = (const float*)d_in[0];
  const int* lens   = (const int*)d_in[1];
  float* dist = (float*)d_ws;

  sdtw_kernel<<<NPAIR, 768, 0, stream>>>(data, lens, dist);
  loss_kernel<<<1, 64, 0, stream>>>(dist, (float*)d_out);
}

// Round 18
// 133.860 us; speedup vs baseline: 9.1682x; 1.2246x over previous
//
#include <hip/hip_runtime.h>
#include <hip/hip_fp16.h>

#define LQ 384
#define DF 64
#define NWIN 16
#define PERW 15      // NG + NF
#define STEPW 16     // 1 + NG + NF
#define NPAIR 240    // NWIN * PERW
#define NWAVE 6      // row-slabs (producer waves and consumer waves each)
#define PW 32        // panel width (cols per round)
#define NPANEL 12    // 384 / PW
#define NROUND2 18   // NPANEL + NWAVE - 1 + 1 (producer lead)
#define BSTH 72      // fp16 B LDS row stride (halfs); 144 B = 16B-aligned rows
#define DRS 36       // fp16 D-tile ROW stride (halfs); 72 B, 8B-aligned
#define C2  0.28853900817779268f   // 1/(5*ln2)  (pre-scale: R' = R*C2)
#define L2C 3.4657359027997265f    // 5*ln2      (unscale at extraction)
#define BIGS (1e9f * C2)           // BIG in scaled domain

typedef _Float16 h16x8 __attribute__((ext_vector_type(8)));
typedef float    f32x16 __attribute__((ext_vector_type(16)));

__device__ __forceinline__ float fexp2(float x) { return __builtin_amdgcn_exp2f(x); }
__device__ __forceinline__ float flog2(float x) { return __builtin_amdgcn_logf(x); }

// wave_shr:1 -- lane l gets lane l-1's value (VALU pipe). lane0 keeps own (fixed up).
__device__ __forceinline__ float wshr1f(float x) {
  int xi = __float_as_int(x);
  return __int_as_float(__builtin_amdgcn_update_dpp(xi, xi, 0x138, 0xF, 0xF, false));
}
__device__ __forceinline__ float rdlane(float v, int l) {
  return __int_as_float(__builtin_amdgcn_readlane(__float_as_int(v), l));
}

// ---------------------------------------------------------------------------
// Producer-consumer soft-DTW. Consumers: r16-validated register DP chain
// (med3 softmin). Producers on MFMA (v_mfma_f32_32x32x16_f16): 8 MFMA per
// 64x32 D panel; B fragments = 1 ds_read_b128 each (vs 128 ds_read_b64/round
// before -- the CU's single LDS pipe was the shared wall). A fragments from
// global f32 + scalar _Float16 casts (RTN). C/D layout per m74/m101:
// col=lane&31, row=(reg&3)+8*(reg>>2)+4*(lane>>5).
// ---------------------------------------------------------------------------
__global__ __launch_bounds__(768, 3) void sdtw_kernel(const float* __restrict__ data,
                                                      const int* __restrict__ lens,
                                                      float* __restrict__ dist) {
  __shared__ __align__(16) __half BshH[LQ * BSTH];           // 55296 B (B in fp16)
  __shared__ __align__(16) __half DtH[2][NWAVE][64 * DRS];   // 55296 B (D*C2, fp16)
  __shared__ __align__(16) float  sqA[LQ];                   // 1536 B
  __shared__ __align__(16) float  sqB[LQ];                   // 1536 B
  __shared__ __align__(16) float  bnd[NWAVE][2][36];         // 1728 B  (115392 total)

  const int p_id = blockIdx.x;
  const int wwin = p_id / PERW;
  const int o = p_id - wwin * PERW;
  const int aRow = wwin * STEPW;
  const int bRow = aRow + 1 + o;
  const int la = lens[aRow];
  const int lb = lens[bRow];
  const int tid = threadIdx.x;
  const int w = tid >> 6;        // 0..11
  const int lane = tid & 63;

  const float* __restrict__ A  = data + (size_t)aRow * LQ * DF;
  const float* __restrict__ Bp = data + (size_t)bRow * LQ * DF;

  // ---- stage B (fp16) into LDS; sqA/sqB from fp32 global ----
  {
    const float4* B4 = (const float4*)Bp;
    for (int q = tid; q < LQ * 16; q += 768) {
      float4 v = B4[q];
      int row = q >> 4, c4 = (q & 15) << 2;
      uint u0 = __half_as_ushort(__float2half(v.x)) |
                ((uint)__half_as_ushort(__float2half(v.y)) << 16);
      uint u1 = __half_as_ushort(__float2half(v.z)) |
                ((uint)__half_as_ushort(__float2half(v.w)) << 16);
      uint2 qq; qq.x = u0; qq.y = u1;
      *(uint2*)&BshH[row * BSTH + c4] = qq;     // 8B-aligned
    }
  }
  {
    const float* src = (tid < LQ) ? (A + (size_t)tid * DF) : (Bp + (size_t)(tid - LQ) * DF);
    const float4* S4 = (const float4*)src;
    float s = 0.f;
#pragma unroll
    for (int k = 0; k < 16; ++k) {
      float4 v = S4[k];
      s = fmaf(v.x, v.x, s); s = fmaf(v.y, v.y, s);
      s = fmaf(v.z, v.z, s); s = fmaf(v.w, v.w, s);
    }
    if (tid < LQ) sqA[tid] = s; else sqB[tid - LQ] = s;
  }
  __syncthreads();

  // extraction target: R[la][lb] at DP wave wt, lane it, panel pt
  const int wt = (la - 1) >> 6;
  const int it = (la - 1) & 63;
  const int pt = (lb - 1) >> 5;
  const int tstar = it + ((lb - 1) & 31);
  const int rstar2 = wt + pt + 1;               // consumer round index
  const float scale = L2C / (float)(la + lb);

  if (w < NWAVE) {
    // =====================  GEMM (producer) waves: MFMA  ===================
    const int g = w;
    const int colL = lane & 31;                 // M-row / N-col within tile
    const int kh = (lane >> 5) * 8;             // K sub-offset (0 or 8)
    const int rq = 4 * (lane >> 5);             // row offset for C/D mapping
    const bool gActive = (64 * g < la);

    for (int rr = 0; rr < NROUND2; ++rr) {
      __syncthreads();
      const int p = rr - g;
      if ((unsigned)p < (unsigned)NPANEL && gActive && (32 * p < lb)) {
        __half* DtW = &DtH[rr & 1][g][0];
        float sb = sqB[PW * p + colL];
#pragma unroll
        for (int mt = 0; mt < 2; ++mt) {
          const float* arow = A + (size_t)(64 * g + 32 * mt + colL) * DF + kh;
          f32x16 acc;
#pragma unroll
          for (int ii = 0; ii < 16; ++ii) acc[ii] = 0.f;
#pragma unroll
          for (int ks = 0; ks < 4; ++ks) {
            float4 a0 = *(const float4*)(arow + ks * 16);
            float4 a1 = *(const float4*)(arow + ks * 16 + 4);
            h16x8 af;
            af[0] = (_Float16)a0.x; af[1] = (_Float16)a0.y;
            af[2] = (_Float16)a0.z; af[3] = (_Float16)a0.w;
            af[4] = (_Float16)a1.x; af[5] = (_Float16)a1.y;
            af[6] = (_Float16)a1.z; af[7] = (_Float16)a1.w;
            h16x8 bf = *(const h16x8*)&BshH[(size_t)(PW * p + colL) * BSTH + ks * 16 + kh];
            acc = __builtin_amdgcn_mfma_f32_32x32x16_f16(af, bf, acc, 0, 0, 0);
          }
          // epilogue: D' = (sqA[row] + sqB[col] - 2*dot)*C2 -> fp16 RTN store
#pragma unroll
          for (int qq = 0; qq < 4; ++qq) {
            float4 sa = *(const float4*)&sqA[64 * g + 32 * mt + 8 * qq + rq];
            float sas[4] = {sa.x, sa.y, sa.z, sa.w};
#pragma unroll
            for (int ii = 0; ii < 4; ++ii) {
              int reg = qq * 4 + ii;
              int row = 32 * mt + 8 * qq + rq + ii;
              float dv = (sas[ii] + sb - 2.f * acc[reg]) * C2;
              DtW[row * DRS + colL] = __float2half(dv);
            }
          }
        }
      }
    }
  } else {
    // =====================  DP (consumer) waves (r16-validated)  ===========
    const int d = w - NWAVE;                    // 0..5, owns rows 64d+1..64d+64
    const bool dActive = (64 * d < la);
    const int dn = (d + 1 < NWAVE) ? (d + 1) : 0;
    const int l5 = lane & 31;
    float leftR = BIGS;

    for (int rr = 0; rr < NROUND2; ++rr) {
      __syncthreads();
      const int p = rr - 1 - d;
      if ((unsigned)p < (unsigned)NPANEL && dActive && (32 * p < lb)) {
        const __half* DtW = &DtH[(rr - 1) & 1][d][0];

        float* bndR = &bnd[d][rr & 1][0];
        float* bndW = &bnd[dn][(rr + 1) & 1][0];
        const bool wr63 = (lane == 63) && (d + 1 < NWAVE) && (64 * (d + 1) < la);
        if (wr63) bndW[0] = leftR;

        // ---- preload D row, rotated, as FLOAT --------------------------
        const __half* baseA = DtW + (lane * DRS - l5);
        const __half* baseB = baseA + 32;
        float hv[32];
#pragma unroll
        for (int pp = 0; pp < 32; ++pp)
          hv[pp] = __half2float((pp < l5) ? baseB[pp] : baseA[pp]);

        // ---- preload boundary row into one VGPR per lane ----------------
        float vbnd = BIGS;
        if (d > 0 && lane < 36) vbnd = bndR[lane];

        float cur = leftR;
        float extv = 0.f;
        float s2;
        {
          float fix0 = (d == 0) ? ((p == 0) ? 0.f : BIGS) : rdlane(vbnd, 0);
          s2 = (lane == 0) ? fix0 : cur;
        }
        const bool extRound = (d == wt) && (rr == rstar2);

#define STEP(T) do {                                                        \
        float s1 = wshr1f(cur);                                             \
        if ((T) < 32) {                                                     \
          float bup = rdlane(vbnd, (T) + 1);                                \
          s1 = (lane == 0) ? bup : s1;                                      \
        }                                                                   \
        float dv = hv[(T) & 31];                                            \
        float m  = fminf(s2, fminf(s1, cur));            /* v_min3 */       \
        float md = __builtin_amdgcn_fmed3f(s2, s1, cur); /* v_med3 */       \
        float mx = fmaxf(s2, fmaxf(s1, cur));            /* v_max3 */       \
        float e = 1.0f + fexp2(m - md) + fexp2(m - mx);                     \
        float val = dv + m - flog2(e);                                      \
        s2 = s1;                                                            \
        if (extRound && tstar == (T) && lane == it) extv = val;             \
        int jl = (T) - lane;                                                \
        if ((unsigned)jl < 32u) {                                           \
          cur = val;                                                        \
          if ((T) >= 63) { if (wr63) bndW[jl + 1] = val; }                  \
        }                                                                   \
      } while (0)

#pragma unroll
        for (int T = 0; T < 96; ++T) STEP(T);
#undef STEP
        if (extRound && lane == it) dist[p_id] = extv * scale;
        leftR = cur;
      }
    }
  }
}

// ---------------------------------------------------------------------------
// Loss reduction over 16 windows (validated rounds 1-16).
// ---------------------------------------------------------------------------
__device__ __forceinline__ float median5(const float* v) {
#pragma unroll
  for (int i = 0; i < 5; ++i) {
    int c = 0;
#pragma unroll
    for (int j = 0; j < 5; ++j)
      c += (v[j] < v[i]) || ((v[j] == v[i]) && (j < i));
    if (c == 2) return v[i];
  }
  return v[0];
}

__global__ void loss_kernel(const float* __restrict__ dist, float* __restrict__ out) {
  __shared__ float acc[NWIN];
  const int w = threadIdx.x;
  if (w < NWIN) {
    float dg[5], dn[10];
#pragma unroll
    for (int g = 0; g < 5; ++g)  dg[g] = dist[w * PERW + g];
#pragma unroll
    for (int n = 0; n < 10; ++n) dn[n] = dist[w * PERW + 5 + n];

    float lk = 0.f; int nz = 0;
#pragma unroll
    for (int g = 0; g < 5; ++g)
#pragma unroll
      for (int n = 0; n < 10; ++n) {
        float t = dg[g] + 1.0f - dn[n];
        if (t > 0.f) { lk += t; ++nz; }
      }
    float lv = lk / (1.0f + (float)nz);

    float sp = 0.f;
#pragma unroll
    for (int g = 0; g < 5; ++g) sp += dg[g];
    float only_pos = sp * (0.01f / 5.0f);

    float mg = median5(dg);
    float ms = median5(dn);

    int err = 0;
#pragma unroll
    for (int g = 0; g < 5; ++g) {
      err += ((dg[g] < mg) && (dn[g] < mg));
      err += ((dg[g] > ms) && (dn[g] > ms));
      err += ((dg[g] < mg) && (dn[5 + g] < mg));
      err += ((dg[g] > ms) && (dn[5 + g] > ms));
    }
    float offset = (float)err * (1.0f / 50.0f);

    acc[w] = lv + only_pos + offset;
  }
  __syncthreads();
  if (w == 0) {
    float s = 0.f;
#pragma unroll
    for (int i = 0; i < NWIN; ++i) s += acc[i];
    out[0] = s / (float)NWIN;
  }
}

// ---------------------------------------------------------------------------
extern "C" void kernel_launch(void* const* d_in, const int* in_sizes, int n_in,
                              void* d_out, int out_size, void* d_ws, size_t ws_size,
                              hipStream_t stream) {
  const float* data = (const float*)d_in[0];
  const int* lens   = (const int*)d_in[1];
  float* dist = (float*)d_ws;

  sdtw_kernel<<<NPAIR, 768, 0, stream>>>(data, lens, dist);
  loss_kernel<<<1, 64, 0, stream>>>(dist, (float*)d_out);
}